// Round 12
// baseline (7244.599 us; speedup 1.0000x reference)
//
#include <hip/hip_runtime.h>

#define B_TOT 1024
#define L_T   100
#define DIN   32
#define HID   128
#define DOUT  32
#define BT    8       // batch rows per block (half of MFMA M=16; waste is cheap)
#define NBLK  128     // 1024 / 8 -> 128 CUs, 1 block/CU
#define NTHREADS 1024 // 16 waves

typedef _Float16 half8 __attribute__((ext_vector_type(8)));
typedef float    f32x4 __attribute__((ext_vector_type(4)));

// XOR-swizzled index into a [16][128] f16 LDS tile (bank-conflict-free b128 reads)
#define SWZ(r,c) (((r) << 7) + ((c) ^ (((r) & 7) << 3)))

__device__ __forceinline__ float fast_exp2(float x){
#if __has_builtin(__builtin_amdgcn_exp2f)
  return __builtin_amdgcn_exp2f(x);
#else
  float r; asm("v_exp_f32 %0, %1\n\ts_nop 1" : "=v"(r) : "v"(x)); return r;
#endif
}
__device__ __forceinline__ float fast_rcp(float x){
#if __has_builtin(__builtin_amdgcn_rcpf)
  return __builtin_amdgcn_rcpf(x);
#else
  float r; asm("v_rcp_f32 %0, %1\n\ts_nop 1" : "=v"(r) : "v"(x)); return r;
#endif
}
__device__ __forceinline__ float fast_tanh(float x){
  float e = fast_exp2(x * 2.885390081777926f);  // 2*log2(e)
  return 1.0f - 2.0f * fast_rcp(e + 1.0f);
}

// Reorder [N][K] f32 row-major weights into fragment-ready f16 tiles:
// dst[((tile*(K/32)+k0)*64 + lane)*8 + ki], lane = (n&15) + 16*((k>>3)&3)
__global__ void reorder_w(const float* __restrict__ src, _Float16* __restrict__ dst,
                          int N, int K){
  int id = blockIdx.x * 256 + threadIdx.x;
  if (id >= N * K) return;
  int n = id / K, k = id - n * K;
  int tile = n >> 4, nl = n & 15;
  int kq = (k >> 3) & 3, k0 = k >> 5, ki = k & 7;
  int lane = nl + (kq << 4);
  int K32 = K >> 5;
  dst[(((tile * K32 + k0) << 6) + lane) * 8 + ki] = (_Float16)src[id];
}

// VGPR-budget mechanism: static LDS 88,064 B > 81,920 B means only ONE
// 1024-thread block fits per CU, so the backend's occupancy target drops
// to 4 waves/EU -> 128-VGPR budget (instead of the 64 it allocates when
// 2 blocks/CU fit). Round 11 tried a dead 'pad' array - DSE deleted it
// (never read). Here the extra LDS is fused into fbfs, a runtime-read
// array the compiler cannot shrink. The 128-reg budget funds the 2-tile
// register prefetch ring (8 KB in flight/wave) in the biglayer.
__global__ __launch_bounds__(NTHREADS) void cde_main(
    const float* __restrict__ coeffs, const float* __restrict__ times,
    const float* __restrict__ init_b, const float* __restrict__ fb0,
    const float* __restrict__ fb1,    const float* __restrict__ fb2,
    const float* __restrict__ fbf,    const float* __restrict__ dec_b,
    const _Float16* __restrict__ W,   float* __restrict__ out)
{
  __shared__ _Float16 bufA[16*HID];  // activation ping-pong (16 rows; 8 valid)
  __shared__ _Float16 bufB[16*HID];
  __shared__ float zf[BT][HID];      // fp32 master z
  __shared__ float dzs[16][HID];     // vf output (16 rows; 8 valid) + init scratch
  __shared__ float kacc[BT][HID];    // RK4 k-accumulator
  __shared__ float dxs[16][DIN];     // dX/dt (rows 8-15 zeroed once)
  __shared__ float fbfs[HID*DIN + 11264];  // fwf bias + 44 KiB occupancy bloat
  // static LDS total = 88,064 B -> 1 block/CU -> 128-VGPR allocation target

  const int tid  = threadIdx.x;
  const int lane = tid & 63;
  const int w    = tid >> 6;   // wave 0..15
  const int cl   = lane & 15;
  const int g    = lane >> 4;
  const int b0   = blockIdx.x * BT;
  const int cr   = tid >> 7, ccol = tid & 127;  // combine mapping (1 elem/thread)

  const _Float16* W0 = W;
  const _Float16* W1 = W + 16384;
  const _Float16* W2 = W + 32768;
  const _Float16* Wf = W + 49152;   // fwf: 4096x128 -> 256 tiles
  const _Float16* Wi = W + 573440;  // init_w
  const _Float16* Wd = W + 577536;  // dec_w
  const _Float16* Wfw = Wf + w * 16 * 2048;  // this wave's 16 tiles (64 KiB)

  // lgkm-only barrier, two-sided compiler clobbers + sched_barrier pins.
  // vmcnt deliberately NOT drained: all cross-wave deps are LDS-only, so
  // ring-prefetch loads legally stay in flight across barriers.
  auto bar = [&]{
    __builtin_amdgcn_sched_barrier(0);
    asm volatile("s_waitcnt lgkmcnt(0)" ::: "memory");
    __builtin_amdgcn_s_barrier();
    __builtin_amdgcn_sched_barrier(0);
    asm volatile("" ::: "memory");
  };

// Load one 4 KiB Wf tile into a named half8[4] (static indices only)
#define LOADT(DST, IDX) {                                   \
    const _Float16* _tp = Wfw + (IDX)*2048 + lane*8;        \
    DST[0] = *(const half8*)(_tp);                          \
    DST[1] = *(const half8*)(_tp + 512);                    \
    DST[2] = *(const half8*)(_tp + 1024);                   \
    DST[3] = *(const half8*)(_tp + 1536); }

  // fbf biases -> LDS (once); zero-init buffers so garbage rows stay finite
  for (int i = tid; i < HID*DIN; i += NTHREADS) fbfs[i] = fbf[i];
  bufA[tid] = (_Float16)0.f; bufA[tid + 1024] = (_Float16)0.f;
  bufB[tid] = (_Float16)0.f; bufB[tid + 1024] = (_Float16)0.f;
  if (tid < 512) dxs[tid >> 5][tid & 31] = 0.f;

  // ---- init: z0 = coeffs[:,0,:] @ init_w.T + init_b ----
  bar();
  if (tid < BT*DIN){
    int r = tid >> 5, d = tid & 31;
    bufB[SWZ(r, d)] = (_Float16)coeffs[(b0 + r)*(L_T*DIN) + d];
  }
  bar();
  if (w < 8){
    f32x4 acc = {0.f,0.f,0.f,0.f};
    half8 a = *(const half8*)(bufB + SWZ(cl, 8*g));
    half8 b = *(const half8*)(Wi + (w*64 + lane)*8);
    acc = __builtin_amdgcn_mfma_f32_16x16x32_f16(a, b, acc, 0, 0, 0);
    float bn = init_b[w*16 + cl];
#pragma unroll
    for (int r = 0; r < 4; ++r){
      float v = acc[r] + bn;
      dzs[4*g + r][w*16 + cl] = v;                  // f32 scratch (16 rows ok)
      bufA[SWZ(4*g + r, w*16 + cl)] = (_Float16)v;
    }
  }
  bar();
  if (tid < BT*HID) zf[cr][ccol] = dzs[cr][ccol];
  bar();

// Dense HID->HID; B-fragments loaded inline from L2-resident weights.
#define DENSE(IN, OB, WT, BIAS) {                                          \
    f32x4 acc = {0.f,0.f,0.f,0.f};                                         \
    _Pragma("unroll")                                                      \
    for (int kq = 0; kq < 4; ++kq){                                        \
      half8 a = *(const half8*)((IN) + SWZ(cl, kq*32 + 8*g));              \
      half8 b = *(const half8*)((WT) + ((w*4 + kq)*64 + lane)*8);          \
      acc = __builtin_amdgcn_mfma_f32_16x16x32_f16(a, b, acc, 0,0,0);}     \
    float bn = (BIAS)[w*16 + cl];                                          \
    _Pragma("unroll")                                                      \
    for (int r = 0; r < 4; ++r)                                            \
      (OB)[SWZ(4*g + r, w*16 + cl)] = (_Float16)fast_tanh(acc[r] + bn); }

#define DECODER(TS) {                                                      \
    int dw = w - 14;                                                       \
    f32x4 acc = {0.f,0.f,0.f,0.f};                                         \
    _Pragma("unroll")                                                      \
    for (int kq = 0; kq < 4; ++kq){                                        \
      half8 a = *(const half8*)(bufA + SWZ(cl, kq*32 + 8*g));              \
      half8 b = *(const half8*)(Wd + ((dw*4 + kq)*64 + lane)*8);           \
      acc = __builtin_amdgcn_mfma_f32_16x16x32_f16(a, b, acc, 0,0,0);}     \
    float bn = dec_b[dw*16 + cl];                                          \
    if (g < 2){                                                            \
      _Pragma("unroll")                                                    \
      for (int r = 0; r < 4; ++r)                                          \
        out[(b0 + 4*g + r)*(L_T*DOUT) + (TS)*DOUT + dw*16 + cl] = acc[r] + bn; } }

  float dxlo[4], dxhi[4];

  for (int t = 0; t < L_T - 1; ++t){
    // decoder(t) on waves 14/15: bufA (=z_t) is not rewritten until s=0's
    // combine, 4 barriers after these ds_reads drain (at this wave's bar()).
    if (w >= 14) DECODER(t)

    float dt = times[t+1] - times[t];
    if (tid < BT*DIN){
      int r = tid >> 5, d = tid & 31;
      const float* cp = coeffs + (b0 + r)*(L_T*DIN) + t*DIN + d;
      dxs[r][d] = (cp[DIN] - cp[0]) / dt;
    }
    bar();
#pragma unroll
    for (int r = 0; r < 4; ++r){
      dxlo[r] = dxs[4*g + r][cl];        // rows 8-15: zeros -> garbage rows x0
      dxhi[r] = dxs[4*g + r][16 + cl];
    }

    for (int s = 0; s < 4; ++s){
      // prime the ring: tiles 0,1 fly during the 3 dense phases
      half8 cur[4], nxt[4];
      LOADT(cur, 0)
      LOADT(nxt, 1)

      if (w < 8) DENSE(bufA, bufB, W0, fb0)
      bar();
      if (w < 8) DENSE(bufB, bufA, W1, fb1)
      bar();
      if (w < 8) DENSE(bufA, bufB, W2, fb2)
      bar();

      // ---- biglayer: 16 waves, 16 tiles each, 2-tile register ring.
      // Reload a tile's regs right after its MFMAs consume them; the
      // compiler emits counted vmcnt so loads overlap tanh/butterfly.
      {
        half8 af[4];
#pragma unroll
        for (int kq = 0; kq < 4; ++kq)
          af[kq] = *(const half8*)(bufB + SWZ(cl, kq*32 + 8*g));
        float p[4];
#pragma unroll
        for (int hh = 0; hh < 8; ++hh){
          {
            f32x4 acc = {0.f,0.f,0.f,0.f};
            acc = __builtin_amdgcn_mfma_f32_16x16x32_f16(af[0], cur[0], acc, 0,0,0);
            acc = __builtin_amdgcn_mfma_f32_16x16x32_f16(af[1], cur[1], acc, 0,0,0);
            acc = __builtin_amdgcn_mfma_f32_16x16x32_f16(af[2], cur[2], acc, 0,0,0);
            acc = __builtin_amdgcn_mfma_f32_16x16x32_f16(af[3], cur[3], acc, 0,0,0);
            if (hh < 7) LOADT(cur, 2*hh + 2)
            float bn = fbfs[(w*16 + 2*hh)*16 + cl];
#pragma unroll
            for (int r = 0; r < 4; ++r)
              p[r] = fast_tanh(acc[r] + bn) * dxlo[r];
          }
          {
            f32x4 acc = {0.f,0.f,0.f,0.f};
            acc = __builtin_amdgcn_mfma_f32_16x16x32_f16(af[0], nxt[0], acc, 0,0,0);
            acc = __builtin_amdgcn_mfma_f32_16x16x32_f16(af[1], nxt[1], acc, 0,0,0);
            acc = __builtin_amdgcn_mfma_f32_16x16x32_f16(af[2], nxt[2], acc, 0,0,0);
            acc = __builtin_amdgcn_mfma_f32_16x16x32_f16(af[3], nxt[3], acc, 0,0,0);
            if (hh < 7) LOADT(nxt, 2*hh + 3)
            float bn = fbfs[(w*16 + 2*hh + 1)*16 + cl];
#pragma unroll
            for (int r = 0; r < 4; ++r)
              p[r] += fast_tanh(acc[r] + bn) * dxhi[r];
          }
#pragma unroll
          for (int m = 1; m < 16; m <<= 1){
#pragma unroll
            for (int r = 0; r < 4; ++r) p[r] += __shfl_xor(p[r], m, 64);
          }
          if (cl == 0){
#pragma unroll
            for (int r = 0; r < 4; ++r) dzs[4*g + r][w*8 + hh] = p[r];
          }
        }
      }
      bar();

      // ---- RK4 combine (1024 valid elems, 1 per thread)
      if (tid < BT*HID){
        float kv = dzs[cr][ccol];
        float nin;
        if (s == 0){ kacc[cr][ccol] = kv;            nin = zf[cr][ccol] + 0.5f*dt*kv; }
        else if (s == 1){ kacc[cr][ccol] += 2.0f*kv; nin = zf[cr][ccol] + 0.5f*dt*kv; }
        else if (s == 2){ kacc[cr][ccol] += 2.0f*kv; nin = zf[cr][ccol] + dt*kv; }
        else {
          float zn = zf[cr][ccol] + (dt * (1.0f/6.0f)) * (kacc[cr][ccol] + kv);
          zf[cr][ccol] = zn; nin = zn;
        }
        bufA[SWZ(cr, ccol)] = (_Float16)nin;
      }
      bar();
    }
  }
  if (w >= 14) DECODER(L_T - 1)
}

extern "C" void kernel_launch(void* const* d_in, const int* in_sizes, int n_in,
                              void* d_out, int out_size, void* d_ws, size_t ws_size,
                              hipStream_t stream){
  const float* coeffs = (const float*)d_in[0];
  const float* times  = (const float*)d_in[1];
  const float* init_w = (const float*)d_in[2];
  const float* init_b = (const float*)d_in[3];
  const float* fw0    = (const float*)d_in[4];
  const float* fb0    = (const float*)d_in[5];
  const float* fw1    = (const float*)d_in[6];
  const float* fb1    = (const float*)d_in[7];
  const float* fw2    = (const float*)d_in[8];
  const float* fb2    = (const float*)d_in[9];
  const float* fwf    = (const float*)d_in[10];
  const float* fbf    = (const float*)d_in[11];
  const float* dec_w  = (const float*)d_in[12];
  const float* dec_b  = (const float*)d_in[13];
  _Float16* W = (_Float16*)d_ws;

  hipLaunchKernelGGL(reorder_w, dim3(64),   dim3(256), 0, stream, fw0, W,          128, 128);
  hipLaunchKernelGGL(reorder_w, dim3(64),   dim3(256), 0, stream, fw1, W + 16384,  128, 128);
  hipLaunchKernelGGL(reorder_w, dim3(64),   dim3(256), 0, stream, fw2, W + 32768,  128, 128);
  hipLaunchKernelGGL(reorder_w, dim3(2048), dim3(256), 0, stream, fwf, W + 49152,  4096, 128);
  hipLaunchKernelGGL(reorder_w, dim3(16),   dim3(256), 0, stream, init_w, W + 573440, 128, 32);
  hipLaunchKernelGGL(reorder_w, dim3(16),   dim3(256), 0, stream, dec_w,  W + 577536,  32, 128);

  hipLaunchKernelGGL(cde_main, dim3(NBLK), dim3(NTHREADS), 0, stream,
                     coeffs, times, init_b, fb0, fb1, fb2, fbf, dec_b,
                     W, (float*)d_out);
}

// Round 13
// 5059.886 us; speedup vs baseline: 1.4318x; 1.4318x over previous
//
#include <hip/hip_runtime.h>

#define B_TOT 1024
#define L_T   100
#define DIN   32
#define HID   128
#define DOUT  32
#define BT    8       // batch rows per block
#define NBLK  128     // 1024 / 8 -> 128 CUs, 1 block/CU (LDS-forced)
#define NTHREADS 512  // 8 waves: empirically unlocks VGPR>64 (round 1: 96)

typedef _Float16 half8 __attribute__((ext_vector_type(8)));
typedef float    f32x4 __attribute__((ext_vector_type(4)));

// XOR-swizzled index into a [16][128] f16 LDS tile (bank-conflict-free b128 reads)
#define SWZ(r,c) (((r) << 7) + ((c) ^ (((r) & 7) << 3)))

__device__ __forceinline__ float fast_exp2(float x){
#if __has_builtin(__builtin_amdgcn_exp2f)
  return __builtin_amdgcn_exp2f(x);
#else
  float r; asm("v_exp_f32 %0, %1\n\ts_nop 1" : "=v"(r) : "v"(x)); return r;
#endif
}
__device__ __forceinline__ float fast_rcp(float x){
#if __has_builtin(__builtin_amdgcn_rcpf)
  return __builtin_amdgcn_rcpf(x);
#else
  float r; asm("v_rcp_f32 %0, %1\n\ts_nop 1" : "=v"(r) : "v"(x)); return r;
#endif
}
__device__ __forceinline__ float fast_tanh(float x){
  float e = fast_exp2(x * 2.885390081777926f);  // 2*log2(e)
  return 1.0f - 2.0f * fast_rcp(e + 1.0f);
}

// Reorder [N][K] f32 row-major weights into fragment-ready f16 tiles:
// dst[((tile*(K/32)+k0)*64 + lane)*8 + ki], lane = (n&15) + 16*((k>>3)&3)
__global__ void reorder_w(const float* __restrict__ src, _Float16* __restrict__ dst,
                          int N, int K){
  int id = blockIdx.x * 256 + threadIdx.x;
  if (id >= N * K) return;
  int n = id / K, k = id - n * K;
  int tile = n >> 4, nl = n & 15;
  int kq = (k >> 3) & 3, k0 = k >> 5, ki = k & 7;
  int lane = nl + (kq << 4);
  int K32 = K >> 5;
  dst[(((tile * K32 + k0) << 6) + lane) * 8 + ki] = (_Float16)src[id];
}

// VGPR reality (rounds 4-12): 1024-thread workgroups are hard-pinned to 64
// VGPR by the backend (launch_bounds min-waves, waves_per_eu(4,4), and
// 1-block/CU LDS occupancy all failed to move it). 512-thread blocks get
// 96+ (round 1). So: 8 waves/block, 128 blocks, LDS padded >80 KiB to keep
// 1 block/CU. The budget funds a 2-tile register ring per wave (8 KB in
// flight x 8 waves = 64 KB/CU) to drive the Wf L2 stream from the measured
// ~33 B/cyc/CU toward the ~56 B/cyc return-path capability.
__global__ __launch_bounds__(NTHREADS) void cde_main(
    const float* __restrict__ coeffs, const float* __restrict__ times,
    const float* __restrict__ init_b, const float* __restrict__ fb0,
    const float* __restrict__ fb1,    const float* __restrict__ fb2,
    const float* __restrict__ fbf,    const float* __restrict__ dec_b,
    const _Float16* __restrict__ W,   float* __restrict__ out)
{
  __shared__ _Float16 bufA[16*HID];  // activation ping-pong (16 rows; 8 valid)
  __shared__ _Float16 bufB[16*HID];
  __shared__ float zf[BT][HID];      // fp32 master z
  __shared__ float dzs[16][HID];     // vf output (16 rows; 8 valid) + init scratch
  __shared__ float kacc[BT][HID];    // RK4 k-accumulator
  __shared__ float dxs[16][DIN];     // dX/dt (rows 8-15 zeroed once)
  __shared__ float fbfs[HID*DIN + 11264];  // fwf bias + 44 KiB occupancy bloat
  // static LDS total = 88,064 B -> exactly 1 block/CU

  const int tid  = threadIdx.x;
  const int lane = tid & 63;
  const int w    = tid >> 6;   // wave 0..7
  const int cl   = lane & 15;
  const int g    = lane >> 4;
  const int b0   = blockIdx.x * BT;

  const _Float16* W0 = W;
  const _Float16* W1 = W + 16384;
  const _Float16* W2 = W + 32768;
  const _Float16* Wf = W + 49152;   // fwf: 4096x128 -> 256 tiles
  const _Float16* Wi = W + 573440;  // init_w
  const _Float16* Wd = W + 577536;  // dec_w
  const _Float16* Wfw = Wf + w * 32 * 2048;  // this wave's 32 tiles (128 KiB)

  // lgkm-only barrier, two-sided compiler clobbers + sched_barrier pins.
  // vmcnt deliberately NOT drained: all cross-wave deps are LDS-only, so
  // ring-prefetch loads legally stay in flight across barriers.
  auto bar = [&]{
    __builtin_amdgcn_sched_barrier(0);
    asm volatile("s_waitcnt lgkmcnt(0)" ::: "memory");
    __builtin_amdgcn_s_barrier();
    __builtin_amdgcn_sched_barrier(0);
    asm volatile("" ::: "memory");
  };

// Load one 4 KiB Wf tile into a named half8[4] (static element indices)
#define LOADT(DST, IDX) {                                   \
    const _Float16* _tp = Wfw + (IDX)*2048 + lane*8;        \
    DST[0] = *(const half8*)(_tp);                          \
    DST[1] = *(const half8*)(_tp + 512);                    \
    DST[2] = *(const half8*)(_tp + 1024);                   \
    DST[3] = *(const half8*)(_tp + 1536); }

  // fbf biases -> LDS (once); zero-init buffers so garbage rows stay finite
  for (int i = tid; i < HID*DIN; i += NTHREADS) fbfs[i] = fbf[i];
#pragma unroll
  for (int j = 0; j < 4; ++j){
    bufA[tid + 512*j] = (_Float16)0.f;
    bufB[tid + 512*j] = (_Float16)0.f;
  }
  dxs[tid >> 5][tid & 31] = 0.f;

  // ---- init: z0 = coeffs[:,0,:] @ init_w.T + init_b ----
  bar();
  if (tid < BT*DIN){
    int r = tid >> 5, d = tid & 31;
    bufB[SWZ(r, d)] = (_Float16)coeffs[(b0 + r)*(L_T*DIN) + d];
  }
  bar();
  {
    f32x4 acc = {0.f,0.f,0.f,0.f};
    half8 a = *(const half8*)(bufB + SWZ(cl, 8*g));
    half8 b = *(const half8*)(Wi + (w*64 + lane)*8);
    acc = __builtin_amdgcn_mfma_f32_16x16x32_f16(a, b, acc, 0, 0, 0);
    float bn = init_b[w*16 + cl];
#pragma unroll
    for (int r = 0; r < 4; ++r){
      float v = acc[r] + bn;
      dzs[4*g + r][w*16 + cl] = v;                  // f32 scratch (16 rows ok)
      bufA[SWZ(4*g + r, w*16 + cl)] = (_Float16)v;
    }
  }
  bar();
#pragma unroll
  for (int j = 0; j < 2; ++j){
    int e = tid + 512*j;
    zf[e >> 7][e & 127] = dzs[e >> 7][e & 127];
  }
  bar();

// Dense HID->HID, all 8 waves; B-fragments inline from L2-resident weights.
#define DENSE(IN, OB, WT, BIAS) {                                          \
    f32x4 acc = {0.f,0.f,0.f,0.f};                                         \
    _Pragma("unroll")                                                      \
    for (int kq = 0; kq < 4; ++kq){                                        \
      half8 a = *(const half8*)((IN) + SWZ(cl, kq*32 + 8*g));              \
      half8 b = *(const half8*)((WT) + ((w*4 + kq)*64 + lane)*8);          \
      acc = __builtin_amdgcn_mfma_f32_16x16x32_f16(a, b, acc, 0,0,0);}     \
    float bn = (BIAS)[w*16 + cl];                                          \
    _Pragma("unroll")                                                      \
    for (int r = 0; r < 4; ++r)                                            \
      (OB)[SWZ(4*g + r, w*16 + cl)] = (_Float16)fast_tanh(acc[r] + bn); }

#define DECODER(TS) {                                                      \
    int dw = w - 6;                                                        \
    f32x4 acc = {0.f,0.f,0.f,0.f};                                         \
    _Pragma("unroll")                                                      \
    for (int kq = 0; kq < 4; ++kq){                                        \
      half8 a = *(const half8*)(bufA + SWZ(cl, kq*32 + 8*g));              \
      half8 b = *(const half8*)(Wd + ((dw*4 + kq)*64 + lane)*8);           \
      acc = __builtin_amdgcn_mfma_f32_16x16x32_f16(a, b, acc, 0,0,0);}     \
    float bn = dec_b[dw*16 + cl];                                          \
    if (g < 2){                                                            \
      _Pragma("unroll")                                                    \
      for (int r = 0; r < 4; ++r)                                          \
        out[(b0 + 4*g + r)*(L_T*DOUT) + (TS)*DOUT + dw*16 + cl] = acc[r] + bn; } }

  float dxlo[4], dxhi[4];

  for (int t = 0; t < L_T - 1; ++t){
    // decoder(t) on waves 6-7: bufA (=z_t) is not rewritten until s=0's
    // combine, 4 barriers after these ds_reads drain (at this wave's bar()).
    if (w >= 6) DECODER(t)

    float dt = times[t+1] - times[t];
    if (tid < BT*DIN){
      int r = tid >> 5, d = tid & 31;
      const float* cp = coeffs + (b0 + r)*(L_T*DIN) + t*DIN + d;
      dxs[r][d] = (cp[DIN] - cp[0]) / dt;
    }
    bar();
#pragma unroll
    for (int r = 0; r < 4; ++r){
      dxlo[r] = dxs[4*g + r][cl];        // rows 8-15: zeros -> garbage rows x0
      dxhi[r] = dxs[4*g + r][16 + cl];
    }

    for (int s = 0; s < 4; ++s){
      // prime the ring: tiles 0,1 fly during the 3 dense phases
      half8 cur[4], nxt[4];
      LOADT(cur, 0)
      LOADT(nxt, 1)

      DENSE(bufA, bufB, W0, fb0)
      bar();
      DENSE(bufB, bufA, W1, fb1)
      bar();
      DENSE(bufA, bufB, W2, fb2)
      bar();

      // ---- biglayer: 8 waves, 32 tiles each, 2-tile register ring.
      // Reload a tile's regs right after its MFMAs consume them; the
      // compiler emits counted vmcnt so loads overlap tanh/butterfly.
      {
        half8 af[4];
#pragma unroll
        for (int kq = 0; kq < 4; ++kq)
          af[kq] = *(const half8*)(bufB + SWZ(cl, kq*32 + 8*g));
        float p[4];
#pragma unroll
        for (int hh = 0; hh < 16; ++hh){
          {
            f32x4 acc = {0.f,0.f,0.f,0.f};
            acc = __builtin_amdgcn_mfma_f32_16x16x32_f16(af[0], cur[0], acc, 0,0,0);
            acc = __builtin_amdgcn_mfma_f32_16x16x32_f16(af[1], cur[1], acc, 0,0,0);
            acc = __builtin_amdgcn_mfma_f32_16x16x32_f16(af[2], cur[2], acc, 0,0,0);
            acc = __builtin_amdgcn_mfma_f32_16x16x32_f16(af[3], cur[3], acc, 0,0,0);
            if (hh < 15) LOADT(cur, 2*hh + 2)
            float bn = fbfs[(w*32 + 2*hh)*16 + cl];
#pragma unroll
            for (int r = 0; r < 4; ++r)
              p[r] = fast_tanh(acc[r] + bn) * dxlo[r];
          }
          {
            f32x4 acc = {0.f,0.f,0.f,0.f};
            acc = __builtin_amdgcn_mfma_f32_16x16x32_f16(af[0], nxt[0], acc, 0,0,0);
            acc = __builtin_amdgcn_mfma_f32_16x16x32_f16(af[1], nxt[1], acc, 0,0,0);
            acc = __builtin_amdgcn_mfma_f32_16x16x32_f16(af[2], nxt[2], acc, 0,0,0);
            acc = __builtin_amdgcn_mfma_f32_16x16x32_f16(af[3], nxt[3], acc, 0,0,0);
            if (hh < 15) LOADT(nxt, 2*hh + 3)
            float bn = fbfs[(w*32 + 2*hh + 1)*16 + cl];
#pragma unroll
            for (int r = 0; r < 4; ++r)
              p[r] += fast_tanh(acc[r] + bn) * dxhi[r];
          }
#pragma unroll
          for (int m = 1; m < 16; m <<= 1){
#pragma unroll
            for (int r = 0; r < 4; ++r) p[r] += __shfl_xor(p[r], m, 64);
          }
          if (cl == 0){
#pragma unroll
            for (int r = 0; r < 4; ++r) dzs[4*g + r][w*16 + hh] = p[r];
          }
        }
      }
      bar();

      // ---- RK4 combine (1024 valid elems, 2 per thread)
#pragma unroll
      for (int j = 0; j < 2; ++j){
        int e = tid + 512*j;
        int cr = e >> 7, ccol = e & 127;
        float kv = dzs[cr][ccol];
        float nin;
        if (s == 0){ kacc[cr][ccol] = kv;            nin = zf[cr][ccol] + 0.5f*dt*kv; }
        else if (s == 1){ kacc[cr][ccol] += 2.0f*kv; nin = zf[cr][ccol] + 0.5f*dt*kv; }
        else if (s == 2){ kacc[cr][ccol] += 2.0f*kv; nin = zf[cr][ccol] + dt*kv; }
        else {
          float zn = zf[cr][ccol] + (dt * (1.0f/6.0f)) * (kacc[cr][ccol] + kv);
          zf[cr][ccol] = zn; nin = zn;
        }
        bufA[SWZ(cr, ccol)] = (_Float16)nin;
      }
      bar();
    }
  }
  if (w >= 6) DECODER(L_T - 1)
}

extern "C" void kernel_launch(void* const* d_in, const int* in_sizes, int n_in,
                              void* d_out, int out_size, void* d_ws, size_t ws_size,
                              hipStream_t stream){
  const float* coeffs = (const float*)d_in[0];
  const float* times  = (const float*)d_in[1];
  const float* init_w = (const float*)d_in[2];
  const float* init_b = (const float*)d_in[3];
  const float* fw0    = (const float*)d_in[4];
  const float* fb0    = (const float*)d_in[5];
  const float* fw1    = (const float*)d_in[6];
  const float* fb1    = (const float*)d_in[7];
  const float* fw2    = (const float*)d_in[8];
  const float* fb2    = (const float*)d_in[9];
  const float* fwf    = (const float*)d_in[10];
  const float* fbf    = (const float*)d_in[11];
  const float* dec_w  = (const float*)d_in[12];
  const float* dec_b  = (const float*)d_in[13];
  _Float16* W = (_Float16*)d_ws;

  hipLaunchKernelGGL(reorder_w, dim3(64),   dim3(256), 0, stream, fw0, W,          128, 128);
  hipLaunchKernelGGL(reorder_w, dim3(64),   dim3(256), 0, stream, fw1, W + 16384,  128, 128);
  hipLaunchKernelGGL(reorder_w, dim3(64),   dim3(256), 0, stream, fw2, W + 32768,  128, 128);
  hipLaunchKernelGGL(reorder_w, dim3(2048), dim3(256), 0, stream, fwf, W + 49152,  4096, 128);
  hipLaunchKernelGGL(reorder_w, dim3(16),   dim3(256), 0, stream, init_w, W + 573440, 128, 32);
  hipLaunchKernelGGL(reorder_w, dim3(16),   dim3(256), 0, stream, dec_w,  W + 577536,  32, 128);

  hipLaunchKernelGGL(cde_main, dim3(NBLK), dim3(NTHREADS), 0, stream,
                     coeffs, times, init_b, fb0, fb1, fb2, fbf, dec_b,
                     W, (float*)d_out);
}